// Round 15
// baseline (75.067 us; speedup 1.0000x reference)
//
#include <hip/hip_runtime.h>
#include <stdint.h>

#define B_N    16384
#define F_N    512
#define NPAIR  128            // 256 steps (1 pad + 255 sites) fused into 128 pairs per side

typedef float    f32x4  __attribute__((ext_vector_type(4)));
typedef float    f32x2t __attribute__((ext_vector_type(2)));
typedef short    s16x4  __attribute__((ext_vector_type(4)));
typedef short    s16x8  __attribute__((ext_vector_type(8)));
typedef int      i32x2  __attribute__((ext_vector_type(2)));
typedef _Float16 f16x4  __attribute__((ext_vector_type(4)));

// compiler-proof global loads: volatile asm cannot be sunk/deleted/rematerialized
#define GLD4(dst, addr, offlit) \
  asm volatile("global_load_dwordx4 %0, %1, off offset:" offlit : "=v"(dst) : "v"(addr))
#define GLD2(dst, addr) \
  asm volatile("global_load_dwordx2 %0, %1, off" : "=v"(dst) : "v"(addr))
#define WAITV(nlit) \
  asm volatile("s_waitcnt vmcnt(" nlit ")" ::: "memory")

// ws layout (shorts): left pair-frags [0,262144), right [262144,524288),
// M (256 f32) at short 524288, c0 at short 524800.
// per pair-side: 2048 shorts = 4 regions x 512:
//   rg0 = [P00hi|P10hi] per lane, rg1 = [P01hi|P11hi], rg2 = [P00lo|P10lo], rg3 = [P01lo|P11lo]
#define WS_SIDE_STRIDE 262144
#define WS_BYTES_NEEDED ((524800 + 2) * 2)

// ---- K=16 MFMA selection (bf16 preferred, f16 fallback; prep dtype must match) ----
#if __has_builtin(__builtin_amdgcn_mfma_f32_16x16x16bf16_1k)
#define AMODE_BF16 1
static __device__ __forceinline__ f32x4 MFMA16(s16x4 a, s16x4 b, f32x4 c) {
  return __builtin_amdgcn_mfma_f32_16x16x16bf16_1k(a, b, c, 0, 0, 0);
}
#elif __has_builtin(__builtin_amdgcn_mfma_f32_16x16x16_bf16)
#define AMODE_BF16 1
static __device__ __forceinline__ f32x4 MFMA16(s16x4 a, s16x4 b, f32x4 c) {
  return __builtin_amdgcn_mfma_f32_16x16x16_bf16(a, b, c, 0, 0, 0);
}
#else
#define AMODE_BF16 0
static __device__ __forceinline__ f32x4 MFMA16(s16x4 a, s16x4 b, f32x4 c) {
  return __builtin_amdgcn_mfma_f32_16x16x16f16(__builtin_bit_cast(f16x4, a),
                                               __builtin_bit_cast(f16x4, b), c, 0, 0, 0);
}
#endif

// element split: w -> hi + lo in the selected 16-bit dtype (hi truncated, lo exact remainder)
static __device__ __forceinline__ void cvt_split(float w, unsigned short &hi, unsigned short &lo) {
#if AMODE_BF16
  unsigned u = __float_as_uint(w);
  hi = (unsigned short)(u >> 16);
  float rl = w - __uint_as_float((unsigned)hi << 16);
  lo = (unsigned short)(__float_as_uint(rl) >> 16);
#else
  _Float16 h = (_Float16)w;
  hi = __builtin_bit_cast(unsigned short, h);
  _Float16 l = (_Float16)(w - (float)h);
  lo = __builtin_bit_cast(unsigned short, l);
#endif
}

// 4 f32 states -> B operands (k = 4g+i maps directly to st[i]; no cross-lane moves)
static __device__ __forceinline__ void splitB(const float* st, s16x4 &Bh, s16x4 &Bl) {
#if AMODE_BF16
  unsigned ph0 = __builtin_amdgcn_perm(__float_as_uint(st[1]), __float_as_uint(st[0]), 0x07060302u);
  unsigned ph1 = __builtin_amdgcn_perm(__float_as_uint(st[3]), __float_as_uint(st[2]), 0x07060302u);
  float l0 = st[0] - __uint_as_float(__float_as_uint(st[0]) & 0xffff0000u);
  float l1 = st[1] - __uint_as_float(__float_as_uint(st[1]) & 0xffff0000u);
  float l2 = st[2] - __uint_as_float(__float_as_uint(st[2]) & 0xffff0000u);
  float l3 = st[3] - __uint_as_float(__float_as_uint(st[3]) & 0xffff0000u);
  unsigned pl0 = __builtin_amdgcn_perm(__float_as_uint(l1), __float_as_uint(l0), 0x07060302u);
  unsigned pl1 = __builtin_amdgcn_perm(__float_as_uint(l3), __float_as_uint(l2), 0x07060302u);
  i32x2 h; h.x = (int)ph0; h.y = (int)ph1;
  i32x2 l; l.x = (int)pl0; l.y = (int)pl1;
  Bh = __builtin_bit_cast(s16x4, h);
  Bl = __builtin_bit_cast(s16x4, l);
#else
  _Float16 h0 = (_Float16)st[0], h1 = (_Float16)st[1], h2 = (_Float16)st[2], h3 = (_Float16)st[3];
  f16x4 H = {h0, h1, h2, h3};
  f16x4 L = {(_Float16)(st[0] - (float)h0), (_Float16)(st[1] - (float)h1),
             (_Float16)(st[2] - (float)h2), (_Float16)(st[3] - (float)h3)};
  Bh = __builtin_bit_cast(s16x4, H);
  Bl = __builtin_bit_cast(s16x4, L);
#endif
}

static __device__ __forceinline__ s16x4 lo4(s16x8 v) {
  return __builtin_shufflevector(v, v, 0, 1, 2, 3);
}
static __device__ __forceinline__ s16x4 hi4(s16x8 v) {
  return __builtin_shufflevector(v, v, 4, 5, 6, 7);
}

// ---------------- prep: fuse site pairs, emit K=16 MFMA A-frags (natural layout) ------
// (byte-identical to rounds 10/12/14 — verified correct, absmax 0.125)
__global__ __launch_bounds__(256) void mps_prep(
    const float* __restrict__ W0, const float* __restrict__ W_left,
    const float* __restrict__ W_out, const float* __restrict__ W_right,
    const float* __restrict__ WN, const float* __restrict__ d1_w,
    const float* __restrict__ d1_b, const float* __restrict__ d2_w,
    const float* __restrict__ d2_b, unsigned short* __restrict__ ws)
{
  int bid = blockIdx.x;
  if (bid < 256) {
    int side = bid >> 7;
    int pair = bid & 127;
    __shared__ float Wa[512];     // [d*32 + p*16 + e]
    __shared__ float Wb[512];
    __shared__ float Amat[4][256]; // [i*2+j][m*16+k]
    int t = threadIdx.x;
    bool pad_a = (pair == 0);
    const float* base_a = side ? (W_right + (size_t)(255 - 2*pair) * 512)
                               : (W_left  + (size_t)(2*pair - 1) * 512);
    const float* base_b = side ? (W_right + (size_t)(254 - 2*pair) * 512)
                               : (W_left  + (size_t)(2*pair) * 512);
#pragma unroll
    for (int e = t; e < 512; e += 256) {
      float va;
      if (pad_a) { int d = e >> 5, p = (e >> 4) & 1, m = e & 15; va = (p == 0 && d == m) ? 1.f : 0.f; }
      else va = base_a[e];
      Wa[e] = va;
      Wb[e] = base_b[e];
    }
    __syncthreads();
#pragma unroll
    for (int ei = t; ei < 1024; ei += 256) {
      int ij = ei >> 8;            // i*2 + j
      int i_ = ij >> 1, j_ = ij & 1;
      int rem = ei & 255;
      int m = rem >> 4, k = rem & 15;
      float acc = 0.f;
      if (side == 0) {
#pragma unroll
        for (int tt = 0; tt < 16; ++tt) acc += Wa[k*32 + i_*16 + tt] * Wb[tt*32 + j_*16 + m];
      } else {
#pragma unroll
        for (int tt = 0; tt < 16; ++tt) acc += Wb[m*32 + j_*16 + tt] * Wa[tt*32 + i_*16 + k];
      }
      Amat[ij][m*16 + k] = acc;
    }
    __syncthreads();
    {
      int rg = t >> 6, l = t & 63;      // rg: 0=[00h|10h] 1=[01h|11h] 2=[00l|10l] 3=[01l|11l]
      int jj = rg & 1, lo = rg >> 1;
      int m = l & 15, g4 = (l >> 4) * 4;
      s16x8 v8;
#pragma unroll
      for (int i = 0; i < 4; ++i) {
        int k = g4 + i;
        unsigned short h, lw;
        cvt_split(Amat[jj][m*16 + k], h, lw);          // (i=0, j=jj)
        v8[i] = (short)(lo ? lw : h);
        cvt_split(Amat[2 + jj][m*16 + k], h, lw);      // (i=1, j=jj)
        v8[4 + i] = (short)(lo ? lw : h);
      }
      *reinterpret_cast<s16x8*>(ws + (size_t)side * WS_SIDE_STRIDE
                                   + (size_t)pair * 2048 + rg * 512 + l * 8) = v8;
    }
  } else {
    // M[d][e] = sum_o wef[o] * W_out[d][o][e];  c0 = d2_b + sum_h d2_w[h] d1_b[h]
    int t = threadIdx.x;
    int d = t >> 4, e = t & 15;
    float acc = 0.f;
#pragma unroll
    for (int o = 0; o < 8; ++o) {
      float wef = 0.f;
      for (int hh = 0; hh < 24; ++hh) wef += d2_w[hh] * d1_w[hh*8 + o];
      acc += wef * W_out[d*128 + o*16 + e];
    }
    float* wf = reinterpret_cast<float*>(ws);
    wf[262144 + t] = acc;
    if (t == 0) {
      float c0 = d2_b[0];
      for (int hh = 0; hh < 24; ++hh) c0 += d2_w[hh] * d1_b[hh];
      wf[262400] = c0;
    }
  }
}

// ---------------- main: 256 blocks x 8 waves {4L,4R}, 16 samples/wave, 2 waves/SIMD ----
// Direct-L2 register pipeline: NO LDS staging, NO ds_read, NO vmcnt(0)/syncthreads in
// the loop. Volatile-asm global_load_dwordx4/x2 with 4-set register rotation (consume
// set p%4, issue pair p+3 into set (p+3)%4), counted s_waitcnt vmcnt(10) + sched_barrier
// (rule #18). One raw s_barrier per 8 pairs keeps same-CU waves loosely synced (L1 reuse).
__global__ __launch_bounds__(512, 2) void mps_main(
    const float* __restrict__ x, const float* __restrict__ W0,
    const float* __restrict__ WN, const unsigned short* __restrict__ ws,
    float* __restrict__ out)
{
  __shared__ float fin[2][64][16];   // 8 KiB

  const int tidx = threadIdx.x;
  const int wave = tidx >> 6;
  const int lane = tidx & 63;
  const int side = wave >> 2;         // waves 0-3 left, 4-7 right
  const int q    = wave & 3;          // sample group
  const int n    = lane & 15;         // sample column
  const int g    = lane >> 4;         // lane group: rows/k 4g..4g+3
  const int b    = blockIdx.x * 64 + q * 16 + n;
  const float* xrow = x + (size_t)b * F_N;

  // init B: lane-group g holds v0[4g..4g+3]  (normal loads, complete before asm pipeline)
  s16x4 Bh, Bl;
  float st[4];
  {
    float xi0 = side ? xrow[F_N-1] : xrow[0];
#pragma unroll
    for (int i = 0; i < 4; ++i) {
      int j = g*4 + i;
      float a0 = side ? WN[j*2]   : W0[j];
      float a1 = side ? WN[j*2+1] : W0[16+j];
      st[i] = fmaf(xi0, a1, a0);
    }
    splitB(st, Bh, Bl);
  }

  f32x4 Dz = {0.f, 0.f, 0.f, 0.f};

  // rolling pointers: frag pair base (4096 B/pair) and x (one dwordx2 per pair)
  const unsigned short* fp2 = ws + (size_t)side * WS_SIDE_STRIDE + (size_t)lane * 8;
  const float* xp2 = side ? (xrow + 510) : xrow;
  const int xstep = side ? -2 : 2;

  s16x8 FA0, FA1, FA2, FA3, FB0, FB1, FB2, FB3;
  s16x8 FC0, FC1, FC2, FC3, FD0, FD1, FD2, FD3;
  f32x2t XA, XB, XC, XD;

  // prologue: issue pairs 0,1,2 into sets A,B,C (5 loads per pair)
  GLD4(FA0, fp2, "0"); GLD4(FA1, fp2, "1024"); GLD4(FA2, fp2, "2048"); GLD4(FA3, fp2, "3072");
  GLD2(XA, xp2); fp2 += 2048; xp2 += xstep;
  GLD4(FB0, fp2, "0"); GLD4(FB1, fp2, "1024"); GLD4(FB2, fp2, "2048"); GLD4(FB3, fp2, "3072");
  GLD2(XB, xp2); fp2 += 2048; xp2 += xstep;
  GLD4(FC0, fp2, "0"); GLD4(FC1, fp2, "1024"); GLD4(FC2, fp2, "2048"); GLD4(FC3, fp2, "3072");
  GLD2(XC, xp2); fp2 += 2048; xp2 += xstep;

  // pair body: wait for this pair's set, issue pair p+3 into the set freed last body,
  // then 12 MFMAs (4 independent 3-deep chains) + f32 combine + splitB.
#define PAIR_BODY(Fr0, Fr1, Fr2, Fr3, Xc, Fw0, Fw1, Fw2, Fw3, Xw, ISSUE, WL)            \
  {                                                                                     \
    WAITV(WL);                                                                          \
    __builtin_amdgcn_sched_barrier(0);                                                  \
    if (ISSUE) {                                                                        \
      GLD4(Fw0, fp2, "0"); GLD4(Fw1, fp2, "1024");                                      \
      GLD4(Fw2, fp2, "2048"); GLD4(Fw3, fp2, "3072");                                   \
      GLD2(Xw, xp2); fp2 += 2048; xp2 += xstep;                                         \
    }                                                                                   \
    float xa_ = side ? (float)Xc.y : (float)Xc.x;                                       \
    float xb_ = side ? (float)Xc.x : (float)Xc.y;                                       \
    s16x4 a00h = lo4(Fr0), a10h = hi4(Fr0);                                             \
    s16x4 a01h = lo4(Fr1), a11h = hi4(Fr1);                                             \
    s16x4 a00l = lo4(Fr2), a10l = hi4(Fr2);                                             \
    s16x4 a01l = lo4(Fr3), a11l = hi4(Fr3);                                             \
    f32x4 D00 = MFMA16(a00h, Bh, Dz);                                                   \
    f32x4 D10 = MFMA16(a10h, Bh, Dz);                                                   \
    f32x4 D01 = MFMA16(a01h, Bh, Dz);                                                   \
    f32x4 D11 = MFMA16(a11h, Bh, Dz);                                                   \
    D00 = MFMA16(a00h, Bl, D00);                                                        \
    D10 = MFMA16(a10h, Bl, D10);                                                        \
    D01 = MFMA16(a01h, Bl, D01);                                                        \
    D11 = MFMA16(a11h, Bl, D11);                                                        \
    D00 = MFMA16(a00l, Bh, D00);                                                        \
    D10 = MFMA16(a10l, Bh, D10);                                                        \
    D01 = MFMA16(a01l, Bh, D01);                                                        \
    D11 = MFMA16(a11l, Bh, D11);                                                        \
    _Pragma("unroll")                                                                   \
    for (int r = 0; r < 4; ++r) {                                                       \
      float t0 = fmaf(xa_, D10[r], D00[r]);                                             \
      float t1 = fmaf(xa_, D11[r], D01[r]);                                             \
      st[r] = fmaf(xb_, t1, t0);                                                        \
    }                                                                                   \
    splitB(st, Bh, Bl);                                                                 \
  }

#pragma unroll 1
  for (int c = 0; c < 15; ++c) {     // steady chunks: p = c*8 .. c*8+7, all issue, vmcnt(10)
    PAIR_BODY(FA0, FA1, FA2, FA3, XA, FD0, FD1, FD2, FD3, XD, 1, "10");
    PAIR_BODY(FB0, FB1, FB2, FB3, XB, FA0, FA1, FA2, FA3, XA, 1, "10");
    PAIR_BODY(FC0, FC1, FC2, FC3, XC, FB0, FB1, FB2, FB3, XB, 1, "10");
    PAIR_BODY(FD0, FD1, FD2, FD3, XD, FC0, FC1, FC2, FC3, XC, 1, "10");
    PAIR_BODY(FA0, FA1, FA2, FA3, XA, FD0, FD1, FD2, FD3, XD, 1, "10");
    PAIR_BODY(FB0, FB1, FB2, FB3, XB, FA0, FA1, FA2, FA3, XA, 1, "10");
    PAIR_BODY(FC0, FC1, FC2, FC3, XC, FB0, FB1, FB2, FB3, XB, 1, "10");
    PAIR_BODY(FD0, FD1, FD2, FD3, XD, FC0, FC1, FC2, FC3, XC, 1, "10");
    __builtin_amdgcn_s_barrier();    // raw barrier: no LDS dep -> no waitcnt drain
  }
  // chunk 15: p = 120..127; issues stop at p=124 (F_127), waits taper 10 -> 5 -> 0
  PAIR_BODY(FA0, FA1, FA2, FA3, XA, FD0, FD1, FD2, FD3, XD, 1, "10");  // 120
  PAIR_BODY(FB0, FB1, FB2, FB3, XB, FA0, FA1, FA2, FA3, XA, 1, "10");  // 121
  PAIR_BODY(FC0, FC1, FC2, FC3, XC, FB0, FB1, FB2, FB3, XB, 1, "10");  // 122
  PAIR_BODY(FD0, FD1, FD2, FD3, XD, FC0, FC1, FC2, FC3, XC, 1, "10");  // 123
  PAIR_BODY(FA0, FA1, FA2, FA3, XA, FD0, FD1, FD2, FD3, XD, 1, "10");  // 124
  PAIR_BODY(FB0, FB1, FB2, FB3, XB, FA0, FA1, FA2, FA3, XA, 0, "10");  // 125
  PAIR_BODY(FC0, FC1, FC2, FC3, XC, FA0, FA1, FA2, FA3, XA, 0, "5");   // 126
  PAIR_BODY(FD0, FD1, FD2, FD3, XD, FA0, FA1, FA2, FA3, XA, 0, "0");   // 127
#undef PAIR_BODY

  // final f32 state (natural rows 4g..4g+3) -> LDS
#pragma unroll
  for (int r = 0; r < 4; ++r) fin[side][q*16 + n][g*4 + r] = st[r];
  __syncthreads();

  // head: y = c0 + v^T M u, 8 threads per sample (64 samples x 8 = 512 threads)
  {
    int s = tidx >> 3, j = tidx & 7;
    const float* Mf = reinterpret_cast<const float*>(ws) + 262144;
    float c0 = reinterpret_cast<const float*>(ws)[262400];
    float acc = 0.f;
#pragma unroll
    for (int dd = 0; dd < 2; ++dd) {
      int d = j*2 + dd;
      float zd = 0.f;
#pragma unroll
      for (int e = 0; e < 16; ++e) zd = fmaf(Mf[d*16 + e], fin[1][s][e], zd);
      acc = fmaf(fin[0][s][d], zd, acc);
    }
    acc += __shfl_xor(acc, 1, 64);
    acc += __shfl_xor(acc, 2, 64);
    acc += __shfl_xor(acc, 4, 64);
    if (j == 0) out[blockIdx.x*64 + s] = acc + c0;
  }
}

extern "C" void kernel_launch(void* const* d_in, const int* in_sizes, int n_in,
                              void* d_out, int out_size, void* d_ws, size_t ws_size,
                              hipStream_t stream)
{
  const float* x       = (const float*)d_in[0];
  const float* W0      = (const float*)d_in[1];
  const float* W_left  = (const float*)d_in[2];
  const float* W_out   = (const float*)d_in[3];
  const float* W_right = (const float*)d_in[4];
  const float* WN      = (const float*)d_in[5];
  const float* d1_w    = (const float*)d_in[6];
  const float* d1_b    = (const float*)d_in[7];
  const float* d2_w    = (const float*)d_in[8];
  const float* d2_b    = (const float*)d_in[9];
  unsigned short* ws   = (unsigned short*)d_ws;
  float* out           = (float*)d_out;

  if (ws_size < (size_t)WS_BYTES_NEEDED) return;

  hipLaunchKernelGGL(mps_prep, dim3(257), dim3(256), 0, stream,
                     W0, W_left, W_out, W_right, WN, d1_w, d1_b, d2_w, d2_b, ws);
  hipLaunchKernelGGL(mps_main, dim3(B_N/64), dim3(512), 0, stream,
                     x, W0, WN, ws, out);
}

// Round 16
// 66.068 us; speedup vs baseline: 1.1362x; 1.1362x over previous
//
#include <hip/hip_runtime.h>
#include <stdint.h>

#define B_N    16384
#define F_N    512
#define NPAIR  128            // 256 steps (1 pad + 255 sites) fused into 128 pairs per side
#define CHUNKP 8              // pairs per staged chunk
#define NCHUNK (NPAIR/CHUNKP)

typedef float    f32x4  __attribute__((ext_vector_type(4)));
typedef short    s16x8  __attribute__((ext_vector_type(8)));
typedef int      i32x4  __attribute__((ext_vector_type(4)));
typedef unsigned u32x2  __attribute__((ext_vector_type(2)));

typedef __attribute__((address_space(3))) const unsigned short* lds_cptr;

// compiler-proof LDS read: volatile asm cannot be sunk/deleted (R11/R12/R13 failure mode)
#define DSR(dst, base, offlit) \
  asm volatile("ds_read_b128 %0, %1 offset:" offlit : "=v"(dst) : "v"(base))

// ws layout (shorts): left pair-frags [0,262144), right [262144,524288),
// M (256 f32) at short 524288, c0 at short 524800.
// per pair-side: 2048 shorts = [A1hi(512)|A1lo(512)|A2hi(512)|A2lo(512)]
#define WS_SIDE_STRIDE 262144
#define WS_BYTES_NEEDED ((524800 + 2) * 2)

// pack 4 floats -> 2 packed-bf16 hi words + 2 lo words (trunc split)
static __device__ __forceinline__ void split4(const float* f, unsigned* ph, unsigned* pl) {
#pragma unroll
  for (int j = 0; j < 2; ++j) {
    float f0 = f[2*j], f1 = f[2*j+1];
    unsigned u0 = __float_as_uint(f0), u1 = __float_as_uint(f1);
    ph[j] = __builtin_amdgcn_perm(u1, u0, 0x07060302u);
    float l0 = f0 - __uint_as_float(u0 & 0xffff0000u);
    float l1 = f1 - __uint_as_float(u1 & 0xffff0000u);
    pl[j] = __builtin_amdgcn_perm(__float_as_uint(l1), __float_as_uint(l0), 0x07060302u);
  }
}

// 8 floats -> 4 hi + 4 lo words (split4 consumes 4 floats / writes 2 words)
static __device__ __forceinline__ void split_pack8(const float* f, unsigned* ph, unsigned* pl) {
  split4(f,     ph,     pl);
  split4(f + 4, ph + 2, pl + 2);
}

// swap32: lo lanes -> (a_own, a_from_hi); hi lanes -> (b_from_lo, b_own)
static __device__ __forceinline__ void swap32p(unsigned a, unsigned b, unsigned &x, unsigned &y) {
#if __has_builtin(__builtin_amdgcn_permlane32_swap)
  u32x2 r = __builtin_amdgcn_permlane32_swap(a, b, false, false);
  x = (unsigned)r.x; y = (unsigned)r.y;
#else
  unsigned oa = (unsigned)__shfl_xor((int)a, 32, 64);
  unsigned ob = (unsigned)__shfl_xor((int)b, 32, 64);
  bool hi = (threadIdx.x & 32) != 0;
  x = hi ? ob : a;
  y = hi ? b  : oa;
#endif
}

static __device__ __forceinline__ s16x8 as_s16x8(const unsigned* p) {
  i32x4 v; v.x = (int)p[0]; v.y = (int)p[1]; v.z = (int)p[2]; v.w = (int)p[3];
  return __builtin_bit_cast(s16x8, v);
}

// tau: swap bits 2<->3 of a 4-bit row index
static __device__ __forceinline__ int tau(int m) {
  return (m & 3) | ((m & 4) << 1) | ((m & 8) >> 1);
}

// ---------------- prep: fuse site pairs, emit 16x16x32 K-stacked MFMA A-frags ----------
// (byte-identical to round 6 — verified correct, absmax 0.125)
// Left pair p: v'' = sum_{i,j} xa^i xb^j P_ij^T v; A1 = [P00^T|P10^T] (K-stacked), A2 = [P01^T|P11^T]
// Right pair p: u'' = sum R_ij xa^i xb^j u; A1 = [R00|R10], A2 = [R01|R11]
// A rows stored tau-permuted so D lane-group G holds natural rows {0,8,4,12}[G]+0..3.
__global__ __launch_bounds__(256) void mps_prep(
    const float* __restrict__ W0, const float* __restrict__ W_left,
    const float* __restrict__ W_out, const float* __restrict__ W_right,
    const float* __restrict__ WN, const float* __restrict__ d1_w,
    const float* __restrict__ d1_b, const float* __restrict__ d2_w,
    const float* __restrict__ d2_b, unsigned short* __restrict__ ws)
{
  int bid = blockIdx.x;
  if (bid < 256) {
    int side = bid >> 7;
    int pair = bid & 127;
    __shared__ float Wa[512];    // [d*32 + p*16 + m]
    __shared__ float Wb[512];
    __shared__ float Af[1024];
    int t = threadIdx.x;
    bool pad_a = (pair == 0);
    const float* base_a = side ? (W_right + (size_t)(255 - 2*pair) * 512)
                               : (W_left  + (size_t)(2*pair - 1) * 512);
    const float* base_b = side ? (W_right + (size_t)(254 - 2*pair) * 512)
                               : (W_left  + (size_t)(2*pair) * 512);
#pragma unroll
    for (int e = t; e < 512; e += 256) {
      float va;
      if (pad_a) { int d = e >> 5, p = (e >> 4) & 1, m = e & 15; va = (p == 0 && d == m) ? 1.f : 0.f; }
      else va = base_a[e];
      Wa[e] = va;
      Wb[e] = base_b[e];
    }
    __syncthreads();
#pragma unroll
    for (int ei = t; ei < 1024; ei += 256) {
      int amat = ei >> 9;          // phys idx of site b
      int rem  = ei & 511;
      int m32  = rem >> 4;
      int k    = rem & 15;
      int pa   = m32 >> 4;         // phys idx of site a
      int m    = tau(m32 & 15);    // tau-permuted output row
      float acc = 0.f;
      if (side == 0) {
#pragma unroll
        for (int j = 0; j < 16; ++j) acc += Wa[k*32 + pa*16 + j] * Wb[j*32 + amat*16 + m];
      } else {
#pragma unroll
        for (int j = 0; j < 16; ++j) acc += Wb[m*32 + amat*16 + j] * Wa[j*32 + pa*16 + k];
      }
      Af[ei] = acc;
    }
    __syncthreads();
    {
      int f = t >> 6, l = t & 63;          // f: 0=A1hi 1=A1lo 2=A2hi 3=A2lo
      int amat = f >> 1, lo = f & 1;
      int m = l & 15, kb = (l >> 4) * 8;
      s16x8 v8;
#pragma unroll
      for (int i = 0; i < 8; ++i) {
        int k = kb + i;
        float w = Af[amat*512 + ((k >> 4)*16 + m)*16 + (k & 15)];
        unsigned u = __float_as_uint(w);
        unsigned short h = (unsigned short)(u >> 16);
        if (lo) {
          float rl = w - __uint_as_float((unsigned)h << 16);
          h = (unsigned short)(__float_as_uint(rl) >> 16);
        }
        v8[i] = (short)h;
      }
      *reinterpret_cast<s16x8*>(ws + (size_t)side * WS_SIDE_STRIDE
                                   + (size_t)pair * 2048 + f * 512 + l * 8) = v8;
    }
  } else {
    // M[d][e] = sum_o wef[o] * W_out[d][o][e];  c0 = d2_b + sum_h d2_w[h] d1_b[h]
    int t = threadIdx.x;
    int d = t >> 4, e = t & 15;
    float acc = 0.f;
#pragma unroll
    for (int o = 0; o < 8; ++o) {
      float wef = 0.f;
      for (int hh = 0; hh < 24; ++hh) wef += d2_w[hh] * d1_w[hh*8 + o];
      acc += wef * W_out[d*128 + o*16 + e];
    }
    float* wf = reinterpret_cast<float*>(ws);
    wf[262144 + t] = acc;
    if (t == 0) {
      float c0 = d2_b[0];
      for (int hh = 0; hh < 24; ++hh) c0 += d2_w[hh] * d1_b[hh];
      wf[262400] = c0;
    }
  }
}

// ---------------- main: 256 blocks x 8 waves {4L,4R}, 16 samples/wave, 2 waves/SIMD ----
// R14 shell (coop LDS staging + inline-asm ds_read rotation, counted lgkmcnt) with R6's
// K=32 math: 6 MFMAs/pair (16x16x32, vv=[v; xa v] K-stacked), tau-permuted A so D->B
// relayout is split4 x2 + 4 permlane32_swap. Half the MFMA issue of the K=16 form.
__global__ __launch_bounds__(512, 2) void mps_main(
    const float* __restrict__ x, const float* __restrict__ W0,
    const float* __restrict__ WN, const unsigned short* __restrict__ ws,
    float* __restrict__ out)
{
  __shared__ __align__(16) unsigned short sbuf[2][2][CHUNKP][4][64][8]; // 128 KiB
  __shared__ float fin[2][64][16];                                      // 8 KiB

  const int tidx = threadIdx.x;
  const int wave = tidx >> 6;
  const int lane = tidx & 63;
  const int side = wave >> 2;         // waves 0-3 left, 4-7 right
  const int q    = wave & 3;          // sample group
  const int n    = lane & 15;         // sample column
  const int g    = lane >> 4;         // lane group (k-range 8g..8g+7)
  const int b    = blockIdx.x * 64 + q * 16 + n;
  const float* xrow = x + (size_t)b * F_N;
  const int rbase = ((g & 1) << 3) | ((g & 2) << 1);   // D natural-row base: 0,8,4,12

  // init B-operand for pair 0: vv = [v0 ; xa*v0]
  unsigned bw[4], bwl[4];
  {
    float xi0 = side ? xrow[F_N-1] : xrow[0];
    float f8[8];
#pragma unroll
    for (int i = 0; i < 8; ++i) {
      int k = g*8 + i;
      int j = k & 15;
      float a0 = side ? WN[j*2]   : W0[j];
      float a1 = side ? WN[j*2+1] : W0[16+j];
      float v0 = fmaf(xi0, a1, a0);
      f8[i] = (g >= 2) ? xi0 * v0 : v0;    // pad's xa multiplies zero matrix
    }
    split_pack8(f8, bw, bwl);
  }

  f32x4 Dz = {0.f, 0.f, 0.f, 0.f};

  // cooperative stage: 64 segments of 1 KB (2 sides x 8 pairs x 4 frags), 8 per wave
  auto stage = [&](int chunk, int db) {
#pragma unroll
    for (int s2 = 0; s2 < 8; ++s2) {
      int seg = wave * 8 + s2;
      int ss  = seg >> 5;
      int rem = seg & 31;
      int pr  = rem >> 2, fg = rem & 3;
      const unsigned short* src = ws + (size_t)ss * WS_SIDE_STRIDE
                                + (size_t)(chunk * CHUNKP + pr) * 2048 + fg * 512 + lane * 8;
      __builtin_amdgcn_global_load_lds(
        (const __attribute__((address_space(1))) void*)src,
        (__attribute__((address_space(3))) void*)(&sbuf[ss][db][pr][fg][0][0]),
        16, 0, 0);
    }
  };

  auto xbase = [&](int c) { return xrow + (side ? (496 - 16*c) : (16*c)); };

  float4 xq0, xq1, xq2, xq3;
  {
    const float* xp = xbase(0);
    xq0 = *reinterpret_cast<const float4*>(xp);
    xq1 = *reinterpret_cast<const float4*>(xp + 4);
    xq2 = *reinterpret_cast<const float4*>(xp + 8);
    xq3 = *reinterpret_cast<const float4*>(xp + 12);
  }

  stage(0, 0);
  asm volatile("s_waitcnt vmcnt(0)" ::: "memory");
  __syncthreads();

  float st[4];
#pragma unroll 1
  for (int c = 0; c < NCHUNK; ++c) {
    float4 xn0 = xq0, xn1 = xq1, xn2 = xq2, xn3 = xq3;
    if (c + 1 < NCHUNK) {
      stage(c + 1, (c + 1) & 1);
      const float* xp = xbase(c + 1);
      xn0 = *reinterpret_cast<const float4*>(xp);
      xn1 = *reinterpret_cast<const float4*>(xp + 4);
      xn2 = *reinterpret_cast<const float4*>(xp + 8);
      xn3 = *reinterpret_cast<const float4*>(xp + 12);
    }

    // x schedule for this chunk (elem i = xbase[i]); xa[8] = next chunk's first xa
    float xa[9], xb[8];
    {
      float e0=xq0.x, e1=xq0.y, e2=xq0.z, e3=xq0.w, e4=xq1.x, e5=xq1.y, e6=xq1.z, e7=xq1.w;
      float e8=xq2.x, e9=xq2.y, e10=xq2.z, e11=xq2.w, e12=xq3.x, e13=xq3.y, e14=xq3.z, e15=xq3.w;
      if (side == 0) {
        xa[0]=e0;  xb[0]=e1;  xa[1]=e2;  xb[1]=e3;
        xa[2]=e4;  xb[2]=e5;  xa[3]=e6;  xb[3]=e7;
        xa[4]=e8;  xb[4]=e9;  xa[5]=e10; xb[5]=e11;
        xa[6]=e12; xb[6]=e13; xa[7]=e14; xb[7]=e15;
        xa[8]=xn0.x;
      } else {
        xa[0]=e15; xb[0]=e14; xa[1]=e13; xb[1]=e12;
        xa[2]=e11; xb[2]=e10; xa[3]=e9;  xb[3]=e8;
        xa[4]=e7;  xb[4]=e6;  xa[5]=e5;  xb[5]=e4;
        xa[6]=e3;  xb[6]=e2;  xa[7]=e1;  xb[7]=e0;
        xa[8]=xn3.w;
      }
    }

    // base LDS address for this chunk's buffer (addrspace(3): 32-bit VGPR)
    lds_cptr base = (lds_cptr)(&sbuf[side][c & 1][0][0][0][0]) + (size_t)lane * 8;

    // prologue: issue pair 0's 4 reads (buffer staged + barriered last chunk)
    s16x8 r0, r1, r2, r3, m0, m1, m2, m3;
    DSR(r0, base, "0");
    DSR(r1, base, "1024");
    DSR(r2, base, "2048");
    DSR(r3, base, "3072");

#pragma unroll
    for (int pr = 0; pr < CHUNKP; ++pr) {
      // issue pair pr+1's reads, then wait only for pair pr's (4 newest stay in flight)
      if (pr + 1 < CHUNKP) {
        lds_cptr bp = base + (pr + 1) * 2048;       // 2048 shorts = 4096 B per pair
        DSR(m0, bp, "0");
        DSR(m1, bp, "1024");
        DSR(m2, bp, "2048");
        DSR(m3, bp, "3072");
        asm volatile("s_waitcnt lgkmcnt(4)" ::: "memory");
      } else {
        asm volatile("s_waitcnt lgkmcnt(0)" ::: "memory");
      }
      __builtin_amdgcn_sched_barrier(0);            // rule #18: pin MFMAs below the wait

      s16x8 Bh = as_s16x8(bw), Bl = as_s16x8(bwl);

      // two parallel 3-deep acc chains: D1 = A1*(vvh+vvl), D2 = A2*(vvh+vvl)
      f32x4 D1 = __builtin_amdgcn_mfma_f32_16x16x32_bf16(r0, Bh, Dz, 0, 0, 0);
      f32x4 D2 = __builtin_amdgcn_mfma_f32_16x16x32_bf16(r2, Bh, Dz, 0, 0, 0);
      D1 = __builtin_amdgcn_mfma_f32_16x16x32_bf16(r0, Bl, D1, 0, 0, 0);
      D2 = __builtin_amdgcn_mfma_f32_16x16x32_bf16(r2, Bl, D2, 0, 0, 0);
      D1 = __builtin_amdgcn_mfma_f32_16x16x32_bf16(r1, Bh, D1, 0, 0, 0);
      D2 = __builtin_amdgcn_mfma_f32_16x16x32_bf16(r3, Bh, D2, 0, 0, 0);

#pragma unroll
      for (int r = 0; r < 4; ++r) st[r] = fmaf(xb[pr], D2[r], D1[r]);

      // build next B: split, then 2 swap32 per precision (verified R6 relayout)
      float xs[4];
#pragma unroll
      for (int r = 0; r < 4; ++r) xs[r] = xa[pr + 1] * st[r];
      unsigned vh2[2], vl2[2], xh2[2], xl2[2];
      split4(st, vh2, vl2);
      split4(xs, xh2, xl2);
      swap32p(vh2[0], xh2[0], bw[0], bw[2]);
      swap32p(vh2[1], xh2[1], bw[1], bw[3]);
      swap32p(vl2[0], xl2[0], bwl[0], bwl[2]);
      swap32p(vl2[1], xl2[1], bwl[1], bwl[3]);

      r0 = m0; r1 = m1; r2 = m2; r3 = m3;
    }
    asm volatile("s_waitcnt vmcnt(0)" ::: "memory");
    __syncthreads();
    xq0 = xn0; xq1 = xn1; xq2 = xn2; xq3 = xn3;
  }

  // final f32 state (natural rows rbase..rbase+3) -> LDS
#pragma unroll
  for (int r = 0; r < 4; ++r) fin[side][q*16 + n][rbase + r] = st[r];
  __syncthreads();

  // head: y = c0 + v^T M u, 8 threads per sample (64 samples x 8 = 512 threads)
  {
    int s = tidx >> 3, j = tidx & 7;
    const float* Mf = reinterpret_cast<const float*>(ws) + 262144;
    float c0 = reinterpret_cast<const float*>(ws)[262400];
    float acc = 0.f;
#pragma unroll
    for (int dd = 0; dd < 2; ++dd) {
      int d = j*2 + dd;
      float zd = 0.f;
#pragma unroll
      for (int e = 0; e < 16; ++e) zd = fmaf(Mf[d*16 + e], fin[1][s][e], zd);
      acc = fmaf(fin[0][s][d], zd, acc);
    }
    acc += __shfl_xor(acc, 1, 64);
    acc += __shfl_xor(acc, 2, 64);
    acc += __shfl_xor(acc, 4, 64);
    if (j == 0) out[blockIdx.x*64 + s] = acc + c0;
  }
}

extern "C" void kernel_launch(void* const* d_in, const int* in_sizes, int n_in,
                              void* d_out, int out_size, void* d_ws, size_t ws_size,
                              hipStream_t stream)
{
  const float* x       = (const float*)d_in[0];
  const float* W0      = (const float*)d_in[1];
  const float* W_left  = (const float*)d_in[2];
  const float* W_out   = (const float*)d_in[3];
  const float* W_right = (const float*)d_in[4];
  const float* WN      = (const float*)d_in[5];
  const float* d1_w    = (const float*)d_in[6];
  const float* d1_b    = (const float*)d_in[7];
  const float* d2_w    = (const float*)d_in[8];
  const float* d2_b    = (const float*)d_in[9];
  unsigned short* ws   = (unsigned short*)d_ws;
  float* out           = (float*)d_out;

  if (ws_size < (size_t)WS_BYTES_NEEDED) return;

  hipLaunchKernelGGL(mps_prep, dim3(257), dim3(256), 0, stream,
                     W0, W_left, W_out, W_right, WN, d1_w, d1_b, d2_w, d2_b, ws);
  hipLaunchKernelGGL(mps_main, dim3(B_N/64), dim3(512), 0, stream,
                     x, W0, WN, ws, out);
}

// Round 17
// 43.223 us; speedup vs baseline: 1.7367x; 1.5285x over previous
//
#include <hip/hip_runtime.h>
#include <stdint.h>

#define B_N    16384
#define F_N    512
#define NPAIR  128            // 256 steps (1 pad + 255 sites) fused into 128 pairs per side
#define CHUNKP 8              // pairs per staged chunk
#define NCHUNK (NPAIR/CHUNKP)

typedef float    f32x4  __attribute__((ext_vector_type(4)));
typedef short    s16x4  __attribute__((ext_vector_type(4)));
typedef short    s16x8  __attribute__((ext_vector_type(8)));
typedef _Float16 f16x4  __attribute__((ext_vector_type(4)));

typedef __attribute__((address_space(3))) const unsigned short* lds_cptr;

// compiler-proof LDS read: volatile asm cannot be sunk/deleted (R11/R12/R13 lesson)
#define DSR(dst, base, offlit) \
  asm volatile("ds_read_b128 %0, %1 offset:" offlit : "=v"(dst) : "v"(base))

// ws layout (shorts): left pair-frags [0,131072), right [131072,262144),
// M (256 f32) at short 262144 (float idx 131072), c0 at float idx 131328.
// per pair-side: 1024 shorts = [A1(512) | A2(512)], A1 = [P00|P10] f16, A2 = [P01|P11] f16
#define WS_SIDE_STRIDE 131072
#define WS_M_F         131072
#define WS_C0_F        131328
#define WS_BYTES_NEEDED ((262656 + 2) * 2)

// f16 K=16 MFMA (ISA: v_mfma_f32_16x16x16_f16, A/B = 2 VGPRs = 4 f16)
static __device__ __forceinline__ f32x4 MFMA16F(s16x4 a, s16x4 b, f32x4 c) {
  return __builtin_amdgcn_mfma_f32_16x16x16f16(__builtin_bit_cast(f16x4, a),
                                               __builtin_bit_cast(f16x4, b), c, 0, 0, 0);
}

// 4 f32 states -> single-precision f16 B operand (RNE casts; k = 4g+i maps to st[i])
static __device__ __forceinline__ s16x4 packB(const float* st) {
  f16x4 H = {(_Float16)st[0], (_Float16)st[1], (_Float16)st[2], (_Float16)st[3]};
  return __builtin_bit_cast(s16x4, H);
}

static __device__ __forceinline__ s16x4 lo4(s16x8 v) {
  return __builtin_shufflevector(v, v, 0, 1, 2, 3);
}
static __device__ __forceinline__ s16x4 hi4(s16x8 v) {
  return __builtin_shufflevector(v, v, 4, 5, 6, 7);
}

// ---------------- prep: fuse site pairs, emit K=16 f16 MFMA A-frags (natural layout) --
// Left pair p: st' = sum_{i,j} xa^i xb^j P_ij^T v, P_ij = Wa_i*Wb_j.  A[m][k] = P_ij[k][m].
// Right pair p: u' = sum_{i,j} xa^i xb^j R_ij u, R_ij = Wb_j*Wa_i.    A[m][k] = R_ij[m][k].
// Frag layout (16x16x16): lane l holds A[m=l&15][k=4*(l>>4)+i], i=0..3 (8B); two
// matrices packed per lane (16B) so one ds_read_b128 fetches both.
__global__ __launch_bounds__(256) void mps_prep(
    const float* __restrict__ W0, const float* __restrict__ W_left,
    const float* __restrict__ W_out, const float* __restrict__ W_right,
    const float* __restrict__ WN, const float* __restrict__ d1_w,
    const float* __restrict__ d1_b, const float* __restrict__ d2_w,
    const float* __restrict__ d2_b, unsigned short* __restrict__ ws)
{
  int bid = blockIdx.x;
  if (bid < 256) {
    int side = bid >> 7;
    int pair = bid & 127;
    __shared__ float Wa[512];     // [d*32 + p*16 + e]
    __shared__ float Wb[512];
    __shared__ float Amat[4][256]; // [i*2+j][m*16+k]
    int t = threadIdx.x;
    bool pad_a = (pair == 0);
    const float* base_a = side ? (W_right + (size_t)(255 - 2*pair) * 512)
                               : (W_left  + (size_t)(2*pair - 1) * 512);
    const float* base_b = side ? (W_right + (size_t)(254 - 2*pair) * 512)
                               : (W_left  + (size_t)(2*pair) * 512);
#pragma unroll
    for (int e = t; e < 512; e += 256) {
      float va;
      if (pad_a) { int d = e >> 5, p = (e >> 4) & 1, m = e & 15; va = (p == 0 && d == m) ? 1.f : 0.f; }
      else va = base_a[e];
      Wa[e] = va;
      Wb[e] = base_b[e];
    }
    __syncthreads();
#pragma unroll
    for (int ei = t; ei < 1024; ei += 256) {
      int ij = ei >> 8;            // i*2 + j
      int i_ = ij >> 1, j_ = ij & 1;
      int rem = ei & 255;
      int m = rem >> 4, k = rem & 15;
      float acc = 0.f;
      if (side == 0) {
#pragma unroll
        for (int tt = 0; tt < 16; ++tt) acc += Wa[k*32 + i_*16 + tt] * Wb[tt*32 + j_*16 + m];
      } else {
#pragma unroll
        for (int tt = 0; tt < 16; ++tt) acc += Wb[m*32 + j_*16 + tt] * Wa[tt*32 + i_*16 + k];
      }
      Amat[ij][m*16 + k] = acc;
    }
    __syncthreads();
    if (t < 128) {
      int rg = t >> 6, l = t & 63;      // rg0 = [P00|P10], rg1 = [P01|P11]
      int m = l & 15, g4 = (l >> 4) * 4;
      s16x8 v8;
#pragma unroll
      for (int i = 0; i < 4; ++i) {
        int k = g4 + i;
        _Float16 h0 = (_Float16)Amat[rg][m*16 + k];        // (i=0, j=rg)
        _Float16 h1 = (_Float16)Amat[2 + rg][m*16 + k];    // (i=1, j=rg)
        v8[i]     = __builtin_bit_cast(short, h0);
        v8[4 + i] = __builtin_bit_cast(short, h1);
      }
      *reinterpret_cast<s16x8*>(ws + (size_t)side * WS_SIDE_STRIDE
                                   + (size_t)pair * 1024 + rg * 512 + l * 8) = v8;
    }
  } else {
    // M[d][e] = sum_o wef[o] * W_out[d][o][e];  c0 = d2_b + sum_h d2_w[h] d1_b[h]
    int t = threadIdx.x;
    int d = t >> 4, e = t & 15;
    float acc = 0.f;
#pragma unroll
    for (int o = 0; o < 8; ++o) {
      float wef = 0.f;
      for (int hh = 0; hh < 24; ++hh) wef += d2_w[hh] * d1_w[hh*8 + o];
      acc += wef * W_out[d*128 + o*16 + e];
    }
    float* wf = reinterpret_cast<float*>(ws);
    wf[WS_M_F + t] = acc;
    if (t == 0) {
      float c0 = d2_b[0];
      for (int hh = 0; hh < 24; ++hh) c0 += d2_w[hh] * d1_b[hh];
      wf[WS_C0_F] = c0;
    }
  }
}

// ---------------- main: 256 blocks x 8 waves {4L,4R}, 16 samples/wave, 2 waves/SIMD ----
// R14 shell, f16 single-precision math: per pair 2 asm ds_read_b128 + 4 independent
// MFMAs + 12 fmaf + packB. 2-pair ds lookahead (counted lgkmcnt(4), body < LDS latency)
// with 4-register-set rotation. Coop LDS staging (64KB sbuf), one barrier per 8 pairs.
__global__ __launch_bounds__(512, 2) void mps_main(
    const float* __restrict__ x, const float* __restrict__ W0,
    const float* __restrict__ WN, const unsigned short* __restrict__ ws,
    float* __restrict__ out)
{
  __shared__ __align__(16) unsigned short sbuf[2][2][CHUNKP][2][64][8]; // 64 KiB
  __shared__ float fin[2][64][16];                                      // 8 KiB

  const int tidx = threadIdx.x;
  const int wave = tidx >> 6;
  const int lane = tidx & 63;
  const int side = wave >> 2;         // waves 0-3 left, 4-7 right
  const int q    = wave & 3;          // sample group
  const int n    = lane & 15;         // sample column
  const int g    = lane >> 4;         // lane group: rows/k 4g..4g+3
  const int b    = blockIdx.x * 64 + q * 16 + n;
  const float* xrow = x + (size_t)b * F_N;

  // init B: lane-group g holds v0[4g..4g+3]
  s16x4 Bv;
  float st[4];
  {
    float xi0 = side ? xrow[F_N-1] : xrow[0];
#pragma unroll
    for (int i = 0; i < 4; ++i) {
      int j = g*4 + i;
      float a0 = side ? WN[j*2]   : W0[j];
      float a1 = side ? WN[j*2+1] : W0[16+j];
      st[i] = fmaf(xi0, a1, a0);
    }
    Bv = packB(st);
  }

  f32x4 Dz = {0.f, 0.f, 0.f, 0.f};

  // cooperative stage: 32 segments of 1 KB (2 sides x 8 pairs x 2 regions), 4 per wave
  auto stage = [&](int chunk, int db) {
#pragma unroll
    for (int s2 = 0; s2 < 4; ++s2) {
      int seg = wave * 4 + s2;
      int ss  = seg >> 4;
      int rem = seg & 15;
      int pr  = rem >> 1, fg = rem & 1;
      const unsigned short* src = ws + (size_t)ss * WS_SIDE_STRIDE
                                + (size_t)(chunk * CHUNKP + pr) * 1024 + fg * 512 + lane * 8;
      __builtin_amdgcn_global_load_lds(
        (const __attribute__((address_space(1))) void*)src,
        (__attribute__((address_space(3))) void*)(&sbuf[ss][db][pr][fg][0][0]),
        16, 0, 0);
    }
  };

  auto xbase = [&](int c) { return xrow + (side ? (496 - 16*c) : (16*c)); };

  float4 xq0, xq1, xq2, xq3;
  {
    const float* xp = xbase(0);
    xq0 = *reinterpret_cast<const float4*>(xp);
    xq1 = *reinterpret_cast<const float4*>(xp + 4);
    xq2 = *reinterpret_cast<const float4*>(xp + 8);
    xq3 = *reinterpret_cast<const float4*>(xp + 12);
  }

  stage(0, 0);
  asm volatile("s_waitcnt vmcnt(0)" ::: "memory");
  __syncthreads();

#pragma unroll 1
  for (int c = 0; c < NCHUNK; ++c) {
    float4 xn0 = xq0, xn1 = xq1, xn2 = xq2, xn3 = xq3;
    if (c + 1 < NCHUNK) {
      stage(c + 1, (c + 1) & 1);
      const float* xp = xbase(c + 1);
      xn0 = *reinterpret_cast<const float4*>(xp);
      xn1 = *reinterpret_cast<const float4*>(xp + 4);
      xn2 = *reinterpret_cast<const float4*>(xp + 8);
      xn3 = *reinterpret_cast<const float4*>(xp + 12);
    }

    // x schedule for this chunk (elem i = xbase[i])
    float xa[8], xb[8];
    {
      float e0=xq0.x, e1=xq0.y, e2=xq0.z, e3=xq0.w, e4=xq1.x, e5=xq1.y, e6=xq1.z, e7=xq1.w;
      float e8=xq2.x, e9=xq2.y, e10=xq2.z, e11=xq2.w, e12=xq3.x, e13=xq3.y, e14=xq3.z, e15=xq3.w;
      if (side == 0) {
        xa[0]=e0;  xb[0]=e1;  xa[1]=e2;  xb[1]=e3;
        xa[2]=e4;  xb[2]=e5;  xa[3]=e6;  xb[3]=e7;
        xa[4]=e8;  xb[4]=e9;  xa[5]=e10; xb[5]=e11;
        xa[6]=e12; xb[6]=e13; xa[7]=e14; xb[7]=e15;
      } else {
        xa[0]=e15; xb[0]=e14; xa[1]=e13; xb[1]=e12;
        xa[2]=e11; xb[2]=e10; xa[3]=e9;  xb[3]=e8;
        xa[4]=e7;  xb[4]=e6;  xa[5]=e5;  xb[5]=e4;
        xa[6]=e3;  xb[6]=e2;  xa[7]=e1;  xb[7]=e0;
      }
    }

    // base LDS address for this chunk's buffer (addrspace(3): 32-bit VGPR)
    lds_cptr base = (lds_cptr)(&sbuf[side][c & 1][0][0][0][0]) + (size_t)lane * 8;

    // chunk prologue: issue pairs 0,1 (buffer staged + barriered last chunk)
    s16x8 rA0, rA1, rB0, rB1, rC0, rC1, rD0, rD1;
    DSR(rA0, base, "0");    DSR(rA1, base, "1024");
    {
      lds_cptr bp = base + 1024;                    // pair 1 (1024 shorts = 2048 B)
      DSR(rB0, bp, "0");    DSR(rB1, bp, "1024");
    }

    // body: consume set, issue pair pr+2 into the set freed two bodies ago,
    // counted lgkmcnt(4) keeps 2 pairs in flight; taper 2 -> 0 at chunk end.
#define PAIR_BODY(Rc0, Rc1, Wn0, Wn1, PR, ISSUE, WL)                                    \
  {                                                                                     \
    if (ISSUE) {                                                                        \
      lds_cptr bp = base + (PR + 2) * 1024;                                             \
      DSR(Wn0, bp, "0");                                                                \
      DSR(Wn1, bp, "1024");                                                             \
    }                                                                                   \
    asm volatile("s_waitcnt lgkmcnt(" WL ")" ::: "memory");                             \
    __builtin_amdgcn_sched_barrier(0);                                                  \
    s16x4 a00 = lo4(Rc0), a10 = hi4(Rc0);                                               \
    s16x4 a01 = lo4(Rc1), a11 = hi4(Rc1);                                               \
    f32x4 D00 = MFMA16F(a00, Bv, Dz);                                                   \
    f32x4 D10 = MFMA16F(a10, Bv, Dz);                                                   \
    f32x4 D01 = MFMA16F(a01, Bv, Dz);                                                   \
    f32x4 D11 = MFMA16F(a11, Bv, Dz);                                                   \
    _Pragma("unroll")                                                                   \
    for (int r = 0; r < 4; ++r) {                                                       \
      float t0 = fmaf(xa[PR], D10[r], D00[r]);                                          \
      float t1 = fmaf(xa[PR], D11[r], D01[r]);                                          \
      st[r] = fmaf(xb[PR], t1, t0);                                                     \
    }                                                                                   \
    Bv = packB(st);                                                                     \
  }

    PAIR_BODY(rA0, rA1, rC0, rC1, 0, 1, "4");
    PAIR_BODY(rB0, rB1, rD0, rD1, 1, 1, "4");
    PAIR_BODY(rC0, rC1, rA0, rA1, 2, 1, "4");
    PAIR_BODY(rD0, rD1, rB0, rB1, 3, 1, "4");
    PAIR_BODY(rA0, rA1, rC0, rC1, 4, 1, "4");
    PAIR_BODY(rB0, rB1, rD0, rD1, 5, 1, "4");
    PAIR_BODY(rC0, rC1, rA0, rA1, 6, 0, "2");
    PAIR_BODY(rD0, rD1, rA0, rA1, 7, 0, "0");
#undef PAIR_BODY

    asm volatile("s_waitcnt vmcnt(0)" ::: "memory");
    __syncthreads();
    xq0 = xn0; xq1 = xn1; xq2 = xn2; xq3 = xn3;
  }

  // final f32 state (natural rows 4g..4g+3) -> LDS
#pragma unroll
  for (int r = 0; r < 4; ++r) fin[side][q*16 + n][g*4 + r] = st[r];
  __syncthreads();

  // head: y = c0 + v^T M u, 8 threads per sample (64 samples x 8 = 512 threads)
  {
    int s = tidx >> 3, j = tidx & 7;
    const float* Mf = reinterpret_cast<const float*>(ws) + WS_M_F;
    float c0 = reinterpret_cast<const float*>(ws)[WS_C0_F];
    float acc = 0.f;
#pragma unroll
    for (int dd = 0; dd < 2; ++dd) {
      int d = j*2 + dd;
      float zd = 0.f;
#pragma unroll
      for (int e = 0; e < 16; ++e) zd = fmaf(Mf[d*16 + e], fin[1][s][e], zd);
      acc = fmaf(fin[0][s][d], zd, acc);
    }
    acc += __shfl_xor(acc, 1, 64);
    acc += __shfl_xor(acc, 2, 64);
    acc += __shfl_xor(acc, 4, 64);
    if (j == 0) out[blockIdx.x*64 + s] = acc + c0;
  }
}

extern "C" void kernel_launch(void* const* d_in, const int* in_sizes, int n_in,
                              void* d_out, int out_size, void* d_ws, size_t ws_size,
                              hipStream_t stream)
{
  const float* x       = (const float*)d_in[0];
  const float* W0      = (const float*)d_in[1];
  const float* W_left  = (const float*)d_in[2];
  const float* W_out   = (const float*)d_in[3];
  const float* W_right = (const float*)d_in[4];
  const float* WN      = (const float*)d_in[5];
  const float* d1_w    = (const float*)d_in[6];
  const float* d1_b    = (const float*)d_in[7];
  const float* d2_w    = (const float*)d_in[8];
  const float* d2_b    = (const float*)d_in[9];
  unsigned short* ws   = (unsigned short*)d_ws;
  float* out           = (float*)d_out;

  if (ws_size < (size_t)WS_BYTES_NEEDED) return;

  hipLaunchKernelGGL(mps_prep, dim3(257), dim3(256), 0, stream,
                     W0, W_left, W_out, W_right, WN, d1_w, d1_b, d2_w, d2_b, ws);
  hipLaunchKernelGGL(mps_main, dim3(B_N/64), dim3(512), 0, stream,
                     x, W0, WN, ws, out);
}

// Round 19
// 38.401 us; speedup vs baseline: 1.9548x; 1.1256x over previous
//
#include <hip/hip_runtime.h>
#include <stdint.h>

#define B_N    16384
#define F_N    512
#define NPAIR  128            // 256 steps (1 pad + 255 sites) fused into 128 pairs per side
#define CHUNKP 8              // pairs per staged chunk
#define NCHUNK (NPAIR/CHUNKP)

typedef float    f32x4  __attribute__((ext_vector_type(4)));
typedef short    s16x4  __attribute__((ext_vector_type(4)));
typedef short    s16x8  __attribute__((ext_vector_type(8)));
typedef _Float16 f16x4  __attribute__((ext_vector_type(4)));

typedef __attribute__((address_space(3))) const unsigned short* lds_cptr;

// compiler-proof LDS read: volatile asm cannot be sunk/deleted (R11/R12/R13 lesson)
#define DSR(dst, base, offlit) \
  asm volatile("ds_read_b128 %0, %1 offset:" offlit : "=v"(dst) : "v"(base))

// ws layout: frag shorts [0,262144) (left/right 131072 each); M 256 f32 at float idx
// 131072; c0 at float idx 131328; v-states at float idx 131344 (16384 x 16), u-states
// at float idx 131344 + 262144.
#define WS_SIDE_STRIDE 131072
#define WS_M_F         131072
#define WS_C0_F        131328
#define WS_VU_F        131344
#define WS_U_OFF       262144
#define WS_BYTES_NEEDED ((size_t)(WS_VU_F + 2*262144) * 4)

// f16 K=16 MFMA (ISA: v_mfma_f32_16x16x16_f16, A/B = 2 VGPRs = 4 f16)
static __device__ __forceinline__ f32x4 MFMA16F(s16x4 a, s16x4 b, f32x4 c) {
  return __builtin_amdgcn_mfma_f32_16x16x16f16(__builtin_bit_cast(f16x4, a),
                                               __builtin_bit_cast(f16x4, b), c, 0, 0, 0);
}

// 4 f32 states -> single-precision f16 B operand (RNE casts; k = 4g+i maps to st[i])
static __device__ __forceinline__ s16x4 packB(const float* st) {
  f16x4 H = {(_Float16)st[0], (_Float16)st[1], (_Float16)st[2], (_Float16)st[3]};
  return __builtin_bit_cast(s16x4, H);
}

static __device__ __forceinline__ s16x4 lo4(s16x8 v) {
  return __builtin_shufflevector(v, v, 0, 1, 2, 3);
}
static __device__ __forceinline__ s16x4 hi4(s16x8 v) {
  return __builtin_shufflevector(v, v, 4, 5, 6, 7);
}

// ---------------- prep: fuse site pairs, emit K=16 f16 MFMA A-frags (natural layout) --
// (byte-identical to round 17 — verified correct, absmax 0.1875)
__global__ __launch_bounds__(256) void mps_prep(
    const float* __restrict__ W0, const float* __restrict__ W_left,
    const float* __restrict__ W_out, const float* __restrict__ W_right,
    const float* __restrict__ WN, const float* __restrict__ d1_w,
    const float* __restrict__ d1_b, const float* __restrict__ d2_w,
    const float* __restrict__ d2_b, unsigned short* __restrict__ ws)
{
  int bid = blockIdx.x;
  if (bid < 256) {
    int side = bid >> 7;
    int pair = bid & 127;
    __shared__ float Wa[512];     // [d*32 + p*16 + e]
    __shared__ float Wb[512];
    __shared__ float Amat[4][256]; // [i*2+j][m*16+k]
    int t = threadIdx.x;
    bool pad_a = (pair == 0);
    const float* base_a = side ? (W_right + (size_t)(255 - 2*pair) * 512)
                               : (W_left  + (size_t)(2*pair - 1) * 512);
    const float* base_b = side ? (W_right + (size_t)(254 - 2*pair) * 512)
                               : (W_left  + (size_t)(2*pair) * 512);
#pragma unroll
    for (int e = t; e < 512; e += 256) {
      float va;
      if (pad_a) { int d = e >> 5, p = (e >> 4) & 1, m = e & 15; va = (p == 0 && d == m) ? 1.f : 0.f; }
      else va = base_a[e];
      Wa[e] = va;
      Wb[e] = base_b[e];
    }
    __syncthreads();
#pragma unroll
    for (int ei = t; ei < 1024; ei += 256) {
      int ij = ei >> 8;            // i*2 + j
      int i_ = ij >> 1, j_ = ij & 1;
      int rem = ei & 255;
      int m = rem >> 4, k = rem & 15;
      float acc = 0.f;
      if (side == 0) {
#pragma unroll
        for (int tt = 0; tt < 16; ++tt) acc += Wa[k*32 + i_*16 + tt] * Wb[tt*32 + j_*16 + m];
      } else {
#pragma unroll
        for (int tt = 0; tt < 16; ++tt) acc += Wb[m*32 + j_*16 + tt] * Wa[tt*32 + i_*16 + k];
      }
      Amat[ij][m*16 + k] = acc;
    }
    __syncthreads();
    if (t < 128) {
      int rg = t >> 6, l = t & 63;      // rg0 = [P00|P10], rg1 = [P01|P11]
      int m = l & 15, g4 = (l >> 4) * 4;
      s16x8 v8;
#pragma unroll
      for (int i = 0; i < 4; ++i) {
        int k = g4 + i;
        _Float16 h0 = (_Float16)Amat[rg][m*16 + k];        // (i=0, j=rg)
        _Float16 h1 = (_Float16)Amat[2 + rg][m*16 + k];    // (i=1, j=rg)
        v8[i]     = __builtin_bit_cast(short, h0);
        v8[4 + i] = __builtin_bit_cast(short, h1);
      }
      *reinterpret_cast<s16x8*>(ws + (size_t)side * WS_SIDE_STRIDE
                                   + (size_t)pair * 1024 + rg * 512 + l * 8) = v8;
    }
  } else {
    // M[d][e] = sum_o wef[o] * W_out[d][o][e];  c0 = d2_b + sum_h d2_w[h] d1_b[h]
    int t = threadIdx.x;
    int d = t >> 4, e = t & 15;
    float acc = 0.f;
#pragma unroll
    for (int o = 0; o < 8; ++o) {
      float wef = 0.f;
      for (int hh = 0; hh < 24; ++hh) wef += d2_w[hh] * d1_w[hh*8 + o];
      acc += wef * W_out[d*128 + o*16 + e];
    }
    float* wf = reinterpret_cast<float*>(ws);
    wf[WS_M_F + t] = acc;
    if (t == 0) {
      float c0 = d2_b[0];
      for (int hh = 0; hh < 24; ++hh) c0 += d2_w[hh] * d1_b[hh];
      wf[WS_C0_F] = c0;
    }
  }
}

// ---------------- side kernel: 512 blocks x 4 waves, ONE side per block ---------------
// Identical pair body / staging / barriers to the 43.2us champion, but the block is
// 4 same-side waves: per-chunk __syncthreads syncs 4 waves (not 8), and the 2 blocks
// per CU drift independently, hiding each other's stalls. Final v/u -> ws (f32).
__global__ __launch_bounds__(256, 2) void mps_side(
    const float* __restrict__ x, const float* __restrict__ W0,
    const float* __restrict__ WN, unsigned short* __restrict__ ws)
{
  __shared__ __align__(16) unsigned short sbuf[2][CHUNKP][2][64][8]; // 32 KiB

  const int tidx = threadIdx.x;
  const int wave = tidx >> 6;
  const int lane = tidx & 63;
  const int bid  = blockIdx.x;
  const int side = bid >> 8;          // blocks 0-255: left; 256-511: right
  const int sb   = bid & 255;
  const int n    = lane & 15;         // sample column
  const int g    = lane >> 4;         // lane group: rows/k 4g..4g+3
  const int b    = sb * 64 + wave * 16 + n;
  const float* xrow = x + (size_t)b * F_N;

  // init B: lane-group g holds v0[4g..4g+3]
  s16x4 Bv;
  float st[4];
  {
    float xi0 = side ? xrow[F_N-1] : xrow[0];
#pragma unroll
    for (int i = 0; i < 4; ++i) {
      int j = g*4 + i;
      float a0 = side ? WN[j*2]   : W0[j];
      float a1 = side ? WN[j*2+1] : W0[16+j];
      st[i] = fmaf(xi0, a1, a0);
    }
    Bv = packB(st);
  }

  f32x4 Dz = {0.f, 0.f, 0.f, 0.f};

  // cooperative stage: 16 segments of 1 KB (8 pairs x 2 regions), 4 per wave
  auto stage = [&](int chunk, int db) {
#pragma unroll
    for (int s2 = 0; s2 < 4; ++s2) {
      int seg = wave * 4 + s2;
      int pr  = seg >> 1, fg = seg & 1;
      const unsigned short* src = ws + (size_t)side * WS_SIDE_STRIDE
                                + (size_t)(chunk * CHUNKP + pr) * 1024 + fg * 512 + lane * 8;
      __builtin_amdgcn_global_load_lds(
        (const __attribute__((address_space(1))) void*)src,
        (__attribute__((address_space(3))) void*)(&sbuf[db][pr][fg][0][0]),
        16, 0, 0);
    }
  };

  auto xbase = [&](int c) { return xrow + (side ? (496 - 16*c) : (16*c)); };

  float4 xq0, xq1, xq2, xq3;
  {
    const float* xp = xbase(0);
    xq0 = *reinterpret_cast<const float4*>(xp);
    xq1 = *reinterpret_cast<const float4*>(xp + 4);
    xq2 = *reinterpret_cast<const float4*>(xp + 8);
    xq3 = *reinterpret_cast<const float4*>(xp + 12);
  }

  stage(0, 0);
  asm volatile("s_waitcnt vmcnt(0)" ::: "memory");
  __syncthreads();

#pragma unroll 1
  for (int c = 0; c < NCHUNK; ++c) {
    float4 xn0 = xq0, xn1 = xq1, xn2 = xq2, xn3 = xq3;
    if (c + 1 < NCHUNK) {
      stage(c + 1, (c + 1) & 1);
      const float* xp = xbase(c + 1);
      xn0 = *reinterpret_cast<const float4*>(xp);
      xn1 = *reinterpret_cast<const float4*>(xp + 4);
      xn2 = *reinterpret_cast<const float4*>(xp + 8);
      xn3 = *reinterpret_cast<const float4*>(xp + 12);
    }

    // x schedule for this chunk (elem i = xbase[i])
    float xa[8], xb[8];
    {
      float e0=xq0.x, e1=xq0.y, e2=xq0.z, e3=xq0.w, e4=xq1.x, e5=xq1.y, e6=xq1.z, e7=xq1.w;
      float e8=xq2.x, e9=xq2.y, e10=xq2.z, e11=xq2.w, e12=xq3.x, e13=xq3.y, e14=xq3.z, e15=xq3.w;
      if (side == 0) {
        xa[0]=e0;  xb[0]=e1;  xa[1]=e2;  xb[1]=e3;
        xa[2]=e4;  xb[2]=e5;  xa[3]=e6;  xb[3]=e7;
        xa[4]=e8;  xb[4]=e9;  xa[5]=e10; xb[5]=e11;
        xa[6]=e12; xb[6]=e13; xa[7]=e14; xb[7]=e15;
      } else {
        xa[0]=e15; xb[0]=e14; xa[1]=e13; xb[1]=e12;
        xa[2]=e11; xb[2]=e10; xa[3]=e9;  xb[3]=e8;
        xa[4]=e7;  xb[4]=e6;  xa[5]=e5;  xb[5]=e4;
        xa[6]=e3;  xb[6]=e2;  xa[7]=e1;  xb[7]=e0;
      }
    }

    // base LDS address for this chunk's buffer (addrspace(3): 32-bit VGPR)
    lds_cptr base = (lds_cptr)(&sbuf[c & 1][0][0][0][0]) + (size_t)lane * 8;

    // chunk prologue: issue pairs 0,1 (buffer staged + barriered last chunk)
    s16x8 rA0, rA1, rB0, rB1, rC0, rC1, rD0, rD1;
    DSR(rA0, base, "0");    DSR(rA1, base, "1024");
    {
      lds_cptr bp = base + 1024;                    // pair 1 (1024 shorts = 2048 B)
      DSR(rB0, bp, "0");    DSR(rB1, bp, "1024");
    }

#define PAIR_BODY(Rc0, Rc1, Wn0, Wn1, PR, ISSUE, WL)                                    \
  {                                                                                     \
    if (ISSUE) {                                                                        \
      lds_cptr bp = base + (PR + 2) * 1024;                                             \
      DSR(Wn0, bp, "0");                                                                \
      DSR(Wn1, bp, "1024");                                                             \
    }                                                                                   \
    asm volatile("s_waitcnt lgkmcnt(" WL ")" ::: "memory");                             \
    __builtin_amdgcn_sched_barrier(0);                                                  \
    s16x4 a00 = lo4(Rc0), a10 = hi4(Rc0);                                               \
    s16x4 a01 = lo4(Rc1), a11 = hi4(Rc1);                                               \
    f32x4 D00 = MFMA16F(a00, Bv, Dz);                                                   \
    f32x4 D10 = MFMA16F(a10, Bv, Dz);                                                   \
    f32x4 D01 = MFMA16F(a01, Bv, Dz);                                                   \
    f32x4 D11 = MFMA16F(a11, Bv, Dz);                                                   \
    _Pragma("unroll")                                                                   \
    for (int r = 0; r < 4; ++r) {                                                       \
      float t0 = fmaf(xa[PR], D10[r], D00[r]);                                          \
      float t1 = fmaf(xa[PR], D11[r], D01[r]);                                          \
      st[r] = fmaf(xb[PR], t1, t0);                                                     \
    }                                                                                   \
    Bv = packB(st);                                                                     \
  }

    PAIR_BODY(rA0, rA1, rC0, rC1, 0, 1, "4");
    PAIR_BODY(rB0, rB1, rD0, rD1, 1, 1, "4");
    PAIR_BODY(rC0, rC1, rA0, rA1, 2, 1, "4");
    PAIR_BODY(rD0, rD1, rB0, rB1, 3, 1, "4");
    PAIR_BODY(rA0, rA1, rC0, rC1, 4, 1, "4");
    PAIR_BODY(rB0, rB1, rD0, rD1, 5, 1, "4");
    PAIR_BODY(rC0, rC1, rA0, rA1, 6, 0, "2");
    PAIR_BODY(rD0, rD1, rA0, rA1, 7, 0, "0");
#undef PAIR_BODY

    asm volatile("s_waitcnt vmcnt(0)" ::: "memory");
    __syncthreads();
    xq0 = xn0; xq1 = xn1; xq2 = xn2; xq3 = xn3;
  }

  // final f32 state -> ws (v for side 0, u for side 1); rows 4g..4g+3 contiguous
  {
    float* vu = reinterpret_cast<float*>(ws) + WS_VU_F
              + (size_t)side * WS_U_OFF + (size_t)b * 16 + g * 4;
    float4 o = {st[0], st[1], st[2], st[3]};
    *reinterpret_cast<float4*>(vu) = o;
  }
}

// ---------------- head: y = c0 + v^T M u, one thread per sample -----------------------
__global__ __launch_bounds__(256) void mps_head(
    const unsigned short* __restrict__ ws, float* __restrict__ out)
{
  __shared__ float Msh[256];
  __shared__ float c0s;
  const float* wf = reinterpret_cast<const float*>(ws);
  int t = threadIdx.x;
  Msh[t] = wf[WS_M_F + t];
  if (t == 0) c0s = wf[WS_C0_F];
  __syncthreads();

  int s = blockIdx.x * 256 + t;
  const float* vp = wf + WS_VU_F + (size_t)s * 16;
  const float* up = wf + WS_VU_F + WS_U_OFF + (size_t)s * 16;
  float v[16], u[16];
#pragma unroll
  for (int i = 0; i < 4; ++i) {
    float4 a = *reinterpret_cast<const float4*>(vp + i*4);
    float4 c = *reinterpret_cast<const float4*>(up + i*4);
    v[i*4+0]=a.x; v[i*4+1]=a.y; v[i*4+2]=a.z; v[i*4+3]=a.w;
    u[i*4+0]=c.x; u[i*4+1]=c.y; u[i*4+2]=c.z; u[i*4+3]=c.w;
  }
  float acc = 0.f;
#pragma unroll
  for (int d = 0; d < 16; ++d) {
    float zd = 0.f;
#pragma unroll
    for (int e = 0; e < 16; ++e) zd = fmaf(Msh[d*16 + e], u[e], zd);
    acc = fmaf(v[d], zd, acc);
  }
  out[s] = acc + c0s;
}

extern "C" void kernel_launch(void* const* d_in, const int* in_sizes, int n_in,
                              void* d_out, int out_size, void* d_ws, size_t ws_size,
                              hipStream_t stream)
{
  const float* x       = (const float*)d_in[0];
  const float* W0      = (const float*)d_in[1];
  const float* W_left  = (const float*)d_in[2];
  const float* W_out   = (const float*)d_in[3];
  const float* W_right = (const float*)d_in[4];
  const float* WN      = (const float*)d_in[5];
  const float* d1_w    = (const float*)d_in[6];
  const float* d1_b    = (const float*)d_in[7];
  const float* d2_w    = (const float*)d_in[8];
  const float* d2_b    = (const float*)d_in[9];
  unsigned short* ws   = (unsigned short*)d_ws;
  float* out           = (float*)d_out;

  if (ws_size < WS_BYTES_NEEDED) return;

  hipLaunchKernelGGL(mps_prep, dim3(257), dim3(256), 0, stream,
                     W0, W_left, W_out, W_right, WN, d1_w, d1_b, d2_w, d2_b, ws);
  hipLaunchKernelGGL(mps_side, dim3(512), dim3(256), 0, stream,
                     x, W0, WN, ws);
  hipLaunchKernelGGL(mps_head, dim3(B_N/256), dim3(256), 0, stream,
                     ws, out);
}